// Round 1
// baseline (421.088 us; speedup 1.0000x reference)
//
#include <hip/hip_runtime.h>

// DirectionalSeparableConv2D fused single-pass kernel.
// x: (128, 128, 48, 48) f32, NCHW. out: (128, 128, 48, 48) f32.
// Channel layout in: [0,32)=cen, [32,56)=h, [56,80)=v, [80,104)=d1, [104,128)=d2
// Channel layout out: [0,32)=out_cen, then 4x24 dir outputs.

namespace {
constexpr int BB = 128, HH = 48, WIDTH = 48;
constexpr int CEN_IN = 32, DIR_IN = 24, CEN_OUT = 32, DIR_OUT = 24;
constexpr int C_IN  = CEN_IN + 4 * DIR_IN;    // 128
constexpr int C_OUT = CEN_OUT + 4 * DIR_OUT;  // 128
constexpr int HW = HH * WIDTH;                // 2304
}

__global__ __launch_bounds__(256) void dsc_fused(
    const float* __restrict__ x,
    const float* __restrict__ cen_t,   // [32,3,3]
    const float* __restrict__ dir_t,   // [24,5]
    const float* __restrict__ c2c,     // [32,32]
    const float* __restrict__ p2c,     // [32,24]
    const float* __restrict__ d2c,     // [32,24]
    const float* __restrict__ c2d,     // [24,32]
    const float* __restrict__ d2dW,    // [24,24]
    float* __restrict__ out)
{
    const int p  = blockIdx.x * 256 + threadIdx.x;
    const int w  = p % WIDTH;
    const int hp = p / WIDTH;
    const int h  = hp % HH;
    const int b  = hp / HH;

    const float* __restrict__ xb = x   + (size_t)b * C_IN  * HW;
    float* __restrict__       ob = out + (size_t)b * C_OUT * HW;
    const int pix = h * WIDTH + w;

    // Clamped offsets + 0/1 masks for the 5-tap window in each axis.
    int hoff[5], woff[5];
    float hm[5], wm[5];
#pragma unroll
    for (int i = 0; i < 5; ++i) {
        int hh = h + i - 2, ww = w + i - 2;
        bool hv = (unsigned)hh < (unsigned)HH;
        bool wv = (unsigned)ww < (unsigned)WIDTH;
        hoff[i] = (hv ? hh : h) * WIDTH;
        hm[i]   = hv ? 1.f : 0.f;
        woff[i] = wv ? ww : w;
        wm[i]   = wv ? 1.f : 0.f;
    }

    // ---- center 3x3 depthwise conv ----
    int coff[9]; float cm[9];
#pragma unroll
    for (int kh = 0; kh < 3; ++kh)
#pragma unroll
        for (int kw = 0; kw < 3; ++kw) {
            coff[kh*3+kw] = hoff[kh+1] + woff[kw+1];
            cm[kh*3+kw]   = hm[kh+1] * wm[kw+1];
        }

    float yc[CEN_IN];
#pragma unroll
    for (int c = 0; c < CEN_IN; ++c) {
        const float* __restrict__ pc = xb + c * HW;
        float acc = 0.f;
#pragma unroll
        for (int k = 0; k < 9; ++k)
            acc += cen_t[c*9+k] * (pc[coff[k]] * cm[k]);
        yc[c] = acc;
    }

    // ---- fold yc into cen accumulator and shared dir term; yc dies here ----
    float cen_acc[CEN_OUT], od[DIR_OUT];
#pragma unroll
    for (int o = 0; o < CEN_OUT; ++o) {
        float a = 0.f;
#pragma unroll
        for (int c = 0; c < CEN_IN; ++c) a += c2c[o*CEN_IN+c] * yc[c];
        cen_acc[o] = a;
    }
#pragma unroll
    for (int o = 0; o < DIR_OUT; ++o) {
        float a = 0.f;
#pragma unroll
        for (int c = 0; c < CEN_IN; ++c) a += c2d[o*CEN_IN+c] * yc[c];
        od[o] = a;
    }

    // ---- four directional groups ----
    for (int d = 0; d < 4; ++d) {
        int doff[5]; float dm[5];
#pragma unroll
        for (int i = 0; i < 5; ++i) {
            if (d == 0)      { doff[i] = h*WIDTH + woff[i];   dm[i] = wm[i]; }
            else if (d == 1) { doff[i] = hoff[i] + w;         dm[i] = hm[i]; }
            else if (d == 2) { doff[i] = hoff[i] + woff[i];   dm[i] = hm[i]*wm[i]; }
            else             { doff[i] = hoff[i] + woff[4-i]; dm[i] = hm[i]*wm[4-i]; }
        }
        const float* __restrict__ base = xb + (CEN_IN + d*DIR_IN) * HW;

        float yt[DIR_IN];
#pragma unroll
        for (int c = 0; c < DIR_IN; ++c) {
            const float* __restrict__ pc = base + c * HW;
            float a = 0.f;
#pragma unroll
            for (int i = 0; i < 5; ++i)
                a += dir_t[c*5+i] * (pc[doff[i]] * dm[i]);
            yt[c] = a;
        }

        const float* __restrict__ M = (d < 2) ? p2c : d2c;
#pragma unroll
        for (int o = 0; o < CEN_OUT; ++o) {
            float a = cen_acc[o];
#pragma unroll
            for (int c = 0; c < DIR_IN; ++c) a += M[o*DIR_IN+c] * yt[c];
            cen_acc[o] = a;
        }

        float* __restrict__ obd = ob + (size_t)(CEN_OUT + d*DIR_OUT) * HW + pix;
#pragma unroll
        for (int o = 0; o < DIR_OUT; ++o) {
            float a = od[o];
#pragma unroll
            for (int c = 0; c < DIR_IN; ++c) a += d2dW[o*DIR_IN+c] * yt[c];
            obd[o*HW] = a;
        }
    }

#pragma unroll
    for (int o = 0; o < CEN_OUT; ++o) ob[o*HW + pix] = cen_acc[o];
}

extern "C" void kernel_launch(void* const* d_in, const int* in_sizes, int n_in,
                              void* d_out, int out_size, void* d_ws, size_t ws_size,
                              hipStream_t stream) {
    const float* x     = (const float*)d_in[0];
    const float* cen_t = (const float*)d_in[1];
    const float* dir_t = (const float*)d_in[2];
    const float* c2c   = (const float*)d_in[3];
    const float* p2c   = (const float*)d_in[4];
    const float* d2c   = (const float*)d_in[5];
    const float* c2d   = (const float*)d_in[6];
    const float* d2dW  = (const float*)d_in[7];
    float* out = (float*)d_out;

    const int total  = BB * HH * WIDTH;        // 294912 pixels
    const int blocks = total / 256;            // 1152, exact
    dsc_fused<<<blocks, 256, 0, stream>>>(x, cen_t, dir_t, c2c, p2c, d2c, c2d, d2dW, out);
}